// Round 1
// baseline (1466.867 us; speedup 1.0000x reference)
//
#include <hip/hip_runtime.h>
#include <math.h>

#define B_ 8
#define C_ 256
#define H_ 64
#define W_ 64
#define HW_ 4096
#define NPIX (B_*H_*W_)       // 32768
#define NELEM (B_*C_*HW_)     // 8388608

__device__ __forceinline__ float silu_f(float v) { return v / (1.f + expf(-v)); }

// ---------------- K0: weight transposes + zero BN accumulators --------------
__global__ __launch_bounds__(256) void prep_kernel(
    const float* __restrict__ akw,   // (256,256,3,1) [co][ci][n]
    const float* __restrict__ l1w,   // (256,256) [co][ci]
    const float* __restrict__ cvw,   // (256,256) [co][ci]
    float* __restrict__ wt_ak,       // (768,256) [k][co], k=ci*3+n
    float* __restrict__ wt_l1,       // (256,256) [ci][co]
    float* __restrict__ wt_cv,       // (256,256) [ci][co]
    float* __restrict__ bn_acc)      // 512 floats -> zero
{
    int gid = blockIdx.x * 256 + threadIdx.x;   // grid = 1024 blocks -> 262144
    if (gid < 768 * 256) {
        int k = gid >> 8, co = gid & 255;
        wt_ak[gid] = akw[co * 768 + k];
    } else {
        int g2 = gid - 768 * 256;               // 0..65535
        int ci = g2 >> 8, co = g2 & 255;
        wt_l1[g2] = l1w[co * 256 + ci];
        wt_cv[g2] = cvw[co * 256 + ci];
    }
    if (gid < 512) bn_acc[gid] = 0.f;
}

// ---------------- K1: offset conv (3x3, 256->6, pad 1) + bilinear tables ----
__global__ __launch_bounds__(256) void offset_idx_kernel(
    const float* __restrict__ x,     // (B,256,64,64)
    const float* __restrict__ pw,    // (6,256,3,3)
    const float* __restrict__ pb,    // (6,)
    int4*  __restrict__ idx4,        // (B,3,4096)
    float4* __restrict__ wt4)        // (B,3,4096)
{
    int gid = blockIdx.x * 256 + threadIdx.x;   // 0..32767, grid=128
    int j = gid & 63, i = (gid >> 6) & 63, b = gid >> 12;

    float o[6];
    #pragma unroll
    for (int t = 0; t < 6; ++t) o[t] = pb[t];

    const float* xb = x + b * C_ * HW_;
    for (int ci = 0; ci < C_; ++ci) {
        const float* xp = xb + ci * HW_;
        #pragma unroll
        for (int ki = 0; ki < 3; ++ki) {
            int ii = i + ki - 1;
            if (ii < 0 || ii > 63) continue;
            #pragma unroll
            for (int kj = 0; kj < 3; ++kj) {
                int jj = j + kj - 1;
                if (jj < 0 || jj > 63) continue;
                float xv = xp[ii * 64 + jj];
                #pragma unroll
                for (int t = 0; t < 6; ++t)
                    o[t] += pw[(t * 256 + ci) * 9 + ki * 3 + kj] * xv;
            }
        }
    }

    const float pnx[3] = {0.f, 0.f, 1.f};
    const float pny[3] = {0.f, 1.f, 0.f};
    #pragma unroll
    for (int n = 0; n < 3; ++n) {
        float px_ = (float)i + pnx[n] + o[n];
        float py_ = (float)j + pny[n] + o[n + 3];
        float qx = floorf(px_), qy = floorf(py_);
        float qlx = fminf(fmaxf(qx,        0.f), 63.f);
        float qly = fminf(fmaxf(qy,        0.f), 63.f);
        float qrx = fminf(fmaxf(qx + 1.f,  0.f), 63.f);
        float qry = fminf(fmaxf(qy + 1.f,  0.f), 63.f);
        float pxc = fminf(fmaxf(px_,       0.f), 63.f);
        float pyc = fminf(fmaxf(py_,       0.f), 63.f);
        float glt = (1.f + (qlx - pxc)) * (1.f + (qly - pyc));
        float grb = (1.f - (qrx - pxc)) * (1.f - (qry - pyc));
        float glb = (1.f + (qlx - pxc)) * (1.f - (qry - pyc));
        float grt = (1.f - (qrx - pxc)) * (1.f + (qly - pyc));
        int ilx = (int)qlx, ily = (int)qly, irx = (int)qrx, iry = (int)qry;
        int oi = (b * 3 + n) * HW_ + i * 64 + j;
        idx4[oi] = make_int4(ilx * 64 + ily, irx * 64 + iry,
                             ilx * 64 + iry, irx * 64 + ily);
        wt4[oi]  = make_float4(glt, grb, glb, grt);
    }
}

// ---------------- K2: AK conv as gather-fused GEMM + BN partials ------------
// out[b,co,i,j] = sum_{ci,n} Wt[ci*3+n][co] * v[b,ci,n,i,j]
__global__ __launch_bounds__(256) void ak_gemm_kernel(
    const float* __restrict__ x,
    const float* __restrict__ Wt,     // (768,256)
    const int4*  __restrict__ idx4,
    const float4* __restrict__ wt4,
    float* __restrict__ y_raw,        // (B,256,4096)
    float* __restrict__ bn_acc)       // [0:256] sum, [256:512] sumsq
{
    int blk = blockIdx.x;             // grid = 512 : b*64 + i
    int b = blk >> 6, i = blk & 63;
    int tid = threadIdx.x;            // = co

    __shared__ int4  s_idx[192];      // [n*64 + j]
    __shared__ float4 s_wt[192];
    __shared__ float s_v[96 * 64];    // 24 KB, [k_local][j]

    if (tid < 192) {
        int n = tid >> 6, j = tid & 63;
        int oi = (b * 3 + n) * HW_ + i * 64 + j;
        s_idx[tid] = idx4[oi];
        s_wt[tid]  = wt4[oi];
    }

    float acc[64];
    #pragma unroll
    for (int j = 0; j < 64; ++j) acc[j] = 0.f;
    __syncthreads();

    const float* xb = x + b * C_ * HW_;
    for (int c0 = 0; c0 < 256; c0 += 32) {
        // stage v for 32 ci x 3 n x 64 j
        for (int s = tid; s < 96 * 64; s += 256) {
            int k = s >> 6;               // ci_l*3 + n
            int j = s & 63;
            int ci_l = k / 3;
            int n = k - ci_l * 3;
            int4 id  = s_idx[n * 64 + j];
            float4 g = s_wt[n * 64 + j];
            const float* xp = xb + (c0 + ci_l) * HW_;
            s_v[s] = g.x * xp[id.x] + g.y * xp[id.y]
                   + g.z * xp[id.z] + g.w * xp[id.w];
        }
        __syncthreads();

        const float* wp = Wt + (c0 * 3) * 256 + tid;
        #pragma unroll 4
        for (int k = 0; k < 96; ++k) {
            float w = wp[k * 256];
            const float4* vr = (const float4*)(s_v + k * 64);
            #pragma unroll
            for (int jj = 0; jj < 16; ++jj) {
                float4 vv = vr[jj];
                acc[jj * 4 + 0] += w * vv.x;
                acc[jj * 4 + 1] += w * vv.y;
                acc[jj * 4 + 2] += w * vv.z;
                acc[jj * 4 + 3] += w * vv.w;
            }
        }
        __syncthreads();
    }

    float s = 0.f, s2 = 0.f;
    float* op = y_raw + (b * C_ + tid) * HW_ + i * 64;
    #pragma unroll
    for (int jj = 0; jj < 16; ++jj) {
        float4 o = make_float4(acc[jj*4], acc[jj*4+1], acc[jj*4+2], acc[jj*4+3]);
        ((float4*)op)[jj] = o;
        s  += o.x + o.y + o.z + o.w;
        s2 += o.x*o.x + o.y*o.y + o.z*o.z + o.w*o.w;
    }
    atomicAdd(&bn_acc[tid], s);
    atomicAdd(&bn_acc[256 + tid], s2);
}

// ---------------- K3: BN stats -> scale/shift -------------------------------
__global__ __launch_bounds__(256) void bn_stats_kernel(
    const float* __restrict__ bn_acc,
    const float* __restrict__ gamma,
    const float* __restrict__ beta,
    float* __restrict__ scale_shift)   // [0:256] scale, [256:512] shift
{
    int c = threadIdx.x;
    const float inv_n = 1.f / (float)NPIX;
    float m   = bn_acc[c] * inv_n;
    float var = bn_acc[256 + c] * inv_n - m * m;
    float sc  = gamma[c] * rsqrtf(var + 1e-5f);
    scale_shift[c]       = sc;
    scale_shift[256 + c] = beta[c] - m * sc;
}

// ---------------- K4: BN apply + SiLU ---------------------------------------
__global__ __launch_bounds__(256) void bn_silu_kernel(
    const float4* __restrict__ yr,
    const float* __restrict__ ss,
    float4* __restrict__ y1)
{
    int gid = blockIdx.x * 256 + threadIdx.x;  // NELEM/4, grid=8192
    int c = (gid >> 10) & 255;
    float a = ss[c], sh = ss[256 + c];
    float4 v = yr[gid];
    float4 o;
    o.x = silu_f(v.x * a + sh);
    o.y = silu_f(v.y * a + sh);
    o.z = silu_f(v.z * a + sh);
    o.w = silu_f(v.w * a + sh);
    y1[gid] = o;
}

// ---------------- K5: 5x5 depthwise, pad 2 ----------------------------------
__global__ __launch_bounds__(256) void dw5_kernel(
    const float* __restrict__ in, const float* __restrict__ w,
    const float* __restrict__ bias, float* __restrict__ out)
{
    int gid = blockIdx.x * 256 + threadIdx.x;   // grid = 32768
    int j = gid & 63, i = (gid >> 6) & 63;
    int bc = gid >> 12, c = bc & 255;
    const float* ip = in + bc * HW_;
    float acc = bias[c];
    #pragma unroll
    for (int di = 0; di < 5; ++di) {
        int ii = i + di - 2;
        if (ii < 0 || ii > 63) continue;
        #pragma unroll
        for (int dj = 0; dj < 5; ++dj) {
            int jj = j + dj - 2;
            if (jj < 0 || jj > 63) continue;
            acc += w[c * 25 + di * 5 + dj] * ip[ii * 64 + jj];
        }
    }
    out[gid] = acc;
}

// ---------------- K6: 7x7 depthwise, dilation 3, pad 9 ----------------------
__global__ __launch_bounds__(256) void dw7d3_kernel(
    const float* __restrict__ in, const float* __restrict__ w,
    const float* __restrict__ bias, float* __restrict__ out)
{
    int gid = blockIdx.x * 256 + threadIdx.x;   // grid = 32768
    int j = gid & 63, i = (gid >> 6) & 63;
    int bc = gid >> 12, c = bc & 255;
    const float* ip = in + bc * HW_;
    float acc = bias[c];
    #pragma unroll
    for (int ki = 0; ki < 7; ++ki) {
        int ii = i + 3 * ki - 9;
        if (ii < 0 || ii > 63) continue;
        #pragma unroll
        for (int kj = 0; kj < 7; ++kj) {
            int jj = j + 3 * kj - 9;
            if (jj < 0 || jj > 63) continue;
            acc += w[c * 49 + ki * 7 + kj] * ip[ii * 64 + jj];
        }
    }
    out[gid] = acc;
}

// ---------------- K7/K8: 1x1 conv GEMM --------------------------------------
// MODE 0: out = (W@in + bias) * mul          (lka 1x1 then u*attn)
// MODE 1: out = W@in + bias + res            (final conv + residual)
template<int MODE>
__global__ __launch_bounds__(256) void gemm1x1_kernel(
    const float* __restrict__ in,     // (B,256,4096)
    const float* __restrict__ Wt,     // (256,256) [ci][co]
    const float* __restrict__ bias,   // (256,)
    const float* __restrict__ aux,    // mul (MODE0) or res (MODE1)
    float* __restrict__ out)
{
    int blk = blockIdx.x;             // grid = 512 : b*64 + i
    int b = blk >> 6, i = blk & 63;
    int tid = threadIdx.x;            // = co

    __shared__ float s_v[64 * 64];    // 16 KB

    float acc[64];
    #pragma unroll
    for (int j = 0; j < 64; ++j) acc[j] = 0.f;

    for (int c0 = 0; c0 < 256; c0 += 64) {
        for (int s = tid; s < 64 * 64; s += 256) {
            int ci_l = s >> 6, j = s & 63;
            s_v[s] = in[(b * C_ + c0 + ci_l) * HW_ + i * 64 + j];
        }
        __syncthreads();
        const float* wp = Wt + c0 * 256 + tid;
        #pragma unroll 4
        for (int k = 0; k < 64; ++k) {
            float w = wp[k * 256];
            const float4* vr = (const float4*)(s_v + k * 64);
            #pragma unroll
            for (int jj = 0; jj < 16; ++jj) {
                float4 vv = vr[jj];
                acc[jj * 4 + 0] += w * vv.x;
                acc[jj * 4 + 1] += w * vv.y;
                acc[jj * 4 + 2] += w * vv.z;
                acc[jj * 4 + 3] += w * vv.w;
            }
        }
        __syncthreads();
    }

    float bco = bias[tid];
    long base = (long)(b * C_ + tid) * HW_ + i * 64;
    const float4* ax = (const float4*)(aux + base);
    float4* op = (float4*)(out + base);
    #pragma unroll
    for (int jj = 0; jj < 16; ++jj) {
        float4 o = make_float4(acc[jj*4] + bco, acc[jj*4+1] + bco,
                               acc[jj*4+2] + bco, acc[jj*4+3] + bco);
        float4 a = ax[jj];
        if (MODE == 0) { o.x *= a.x; o.y *= a.y; o.z *= a.z; o.w *= a.w; }
        else           { o.x += a.x; o.y += a.y; o.z += a.z; o.w += a.w; }
        op[jj] = o;
    }
}

// ---------------- launch ----------------------------------------------------
extern "C" void kernel_launch(void* const* d_in, const int* in_sizes, int n_in,
                              void* d_out, int out_size, void* d_ws, size_t ws_size,
                              hipStream_t stream) {
    const float* x     = (const float*)d_in[0];
    const float* p_w   = (const float*)d_in[1];
    const float* p_b   = (const float*)d_in[2];
    const float* ak_w  = (const float*)d_in[3];
    const float* ak_g  = (const float*)d_in[4];
    const float* ak_b  = (const float*)d_in[5];
    const float* l0_w  = (const float*)d_in[6];
    const float* l0_b  = (const float*)d_in[7];
    const float* ls_w  = (const float*)d_in[8];
    const float* ls_b  = (const float*)d_in[9];
    const float* l1_w  = (const float*)d_in[10];
    const float* l1_b  = (const float*)d_in[11];
    const float* cv_w  = (const float*)d_in[12];
    const float* cv_b  = (const float*)d_in[13];
    float* out = (float*)d_out;

    float* ws = (float*)d_ws;
    float* wt_ak   = ws;                       // 196608
    float* wt_l1   = wt_ak + 768 * 256;        // 65536
    float* wt_cv   = wt_l1 + 65536;            // 65536
    float* bn_acc  = wt_cv + 65536;            // 512
    float* bn_ss   = bn_acc + 512;             // 512
    int4*  idx4    = (int4*)(bn_ss + 512);     // 98304 int4
    float4* wt4    = (float4*)(idx4 + 98304);  // 98304 float4
    float* bufA    = (float*)(wt4 + 98304);    // NELEM
    float* bufB    = bufA + NELEM;             // NELEM
    float* bufC    = bufB + NELEM;             // NELEM

    prep_kernel<<<1024, 256, 0, stream>>>(ak_w, l1_w, cv_w, wt_ak, wt_l1, wt_cv, bn_acc);
    offset_idx_kernel<<<128, 256, 0, stream>>>(x, p_w, p_b, idx4, wt4);
    ak_gemm_kernel<<<512, 256, 0, stream>>>(x, wt_ak, idx4, wt4, bufA, bn_acc);
    bn_stats_kernel<<<1, 256, 0, stream>>>(bn_acc, ak_g, ak_b, bn_ss);
    bn_silu_kernel<<<NELEM / 4 / 256, 256, 0, stream>>>((const float4*)bufA, bn_ss, (float4*)bufB);
    dw5_kernel<<<NELEM / 256, 256, 0, stream>>>(bufB, l0_w, l0_b, bufA);
    dw7d3_kernel<<<NELEM / 256, 256, 0, stream>>>(bufA, ls_w, ls_b, bufC);
    gemm1x1_kernel<0><<<512, 256, 0, stream>>>(bufC, wt_l1, l1_b, bufB, bufA);
    gemm1x1_kernel<1><<<512, 256, 0, stream>>>(bufA, wt_cv, cv_b, x, out);
}

// Round 2
// 818.299 us; speedup vs baseline: 1.7926x; 1.7926x over previous
//
#include <hip/hip_runtime.h>
#include <math.h>
#include <stdint.h>

#define B_ 8
#define C_ 256
#define HW_ 4096
#define NELEM (B_*C_*HW_)   // 8388608

typedef __attribute__((ext_vector_type(8))) short short8;
typedef __attribute__((ext_vector_type(4))) float f32x4;

__device__ __forceinline__ unsigned short f2bf(float f) {
    union { float f; uint32_t u; } v; v.f = f;
    uint32_t r = v.u + 0x7FFFu + ((v.u >> 16) & 1u);
    return (unsigned short)(r >> 16);
}
__device__ __forceinline__ float silu_f(float v) { return v / (1.f + __expf(-v)); }

// ---------------- K0: fp32 -> bf16 weight conversion ------------------------
// ak_w (256,256,3,1) flat = [co][k=ci*3+n]  -> wak [co][768]   (no transpose!)
// l1_w/cv_w (256,256,1,1) -> [co][ci] direct.
__global__ __launch_bounds__(256) void prep_kernel(
    const float* __restrict__ akw, const float* __restrict__ l1w,
    const float* __restrict__ cvw,
    unsigned short* __restrict__ wak, unsigned short* __restrict__ wl1,
    unsigned short* __restrict__ wcv)
{
    int gid = blockIdx.x * 256 + threadIdx.x;      // grid=1280 -> 327680
    if (gid < 196608) wak[gid] = f2bf(akw[gid]);
    else if (gid < 262144) { int g = gid - 196608; wl1[g] = f2bf(l1w[g]); }
    else { int g = gid - 262144; wcv[g] = f2bf(cvw[g]); }
}

// ---------------- K1: offset conv (3x3, 256->6, pad1) + bilinear tables -----
// block = (b, i-row), 256 thr = 4 ci-groups x 64 cols; LDS-reduce groups.
__global__ __launch_bounds__(256) void offset_idx_kernel(
    const float* __restrict__ x, const float* __restrict__ pw,
    const float* __restrict__ pb,
    int4* __restrict__ idx4, float4* __restrict__ wt4)
{
    int blk = blockIdx.x;              // 512: b*64 + i
    int b = blk >> 6, i = blk & 63;
    int tid = threadIdx.x;
    int g = tid >> 6, j = tid & 63;

    float o[6] = {0.f, 0.f, 0.f, 0.f, 0.f, 0.f};
    const float* xb = x + (b * C_ + g * 64) * HW_;
    for (int cl = 0; cl < 64; ++cl) {
        int ci = g * 64 + cl;
        const float* xp = xb + cl * HW_;
        const float* wp = pw + ci * 9;
        #pragma unroll
        for (int ki = 0; ki < 3; ++ki) {
            int ii = i + ki - 1; if (ii < 0 || ii > 63) continue;
            #pragma unroll
            for (int kj = 0; kj < 3; ++kj) {
                int jj = j + kj - 1; if (jj < 0 || jj > 63) continue;
                float xv = xp[ii * 64 + jj];
                #pragma unroll
                for (int t = 0; t < 6; ++t) o[t] += wp[t * 2304 + ki * 3 + kj] * xv;
            }
        }
    }
    __shared__ float s_o[256 * 6];
    #pragma unroll
    for (int t = 0; t < 6; ++t) s_o[tid * 6 + t] = o[t];
    __syncthreads();
    if (tid < 64) {
        float v[6];
        #pragma unroll
        for (int t = 0; t < 6; ++t)
            v[t] = pb[t] + s_o[(tid) * 6 + t] + s_o[(64 + tid) * 6 + t]
                 + s_o[(128 + tid) * 6 + t] + s_o[(192 + tid) * 6 + t];
        const float pnx[3] = {0.f, 0.f, 1.f};
        const float pny[3] = {0.f, 1.f, 0.f};
        #pragma unroll
        for (int n = 0; n < 3; ++n) {
            float px_ = (float)i + pnx[n] + v[n];
            float py_ = (float)tid + pny[n] + v[n + 3];
            float qx = floorf(px_), qy = floorf(py_);
            float qlx = fminf(fmaxf(qx,       0.f), 63.f);
            float qly = fminf(fmaxf(qy,       0.f), 63.f);
            float qrx = fminf(fmaxf(qx + 1.f, 0.f), 63.f);
            float qry = fminf(fmaxf(qy + 1.f, 0.f), 63.f);
            float pxc = fminf(fmaxf(px_,      0.f), 63.f);
            float pyc = fminf(fmaxf(py_,      0.f), 63.f);
            float glt = (1.f + (qlx - pxc)) * (1.f + (qly - pyc));
            float grb = (1.f - (qrx - pxc)) * (1.f - (qry - pyc));
            float glb = (1.f + (qlx - pxc)) * (1.f - (qry - pyc));
            float grt = (1.f - (qrx - pxc)) * (1.f + (qly - pyc));
            int ilx = (int)qlx, ily = (int)qly, irx = (int)qrx, iry = (int)qry;
            int oi = (b * 3 + n) * HW_ + i * 64 + tid;
            idx4[oi] = make_int4(ilx * 64 + ily, irx * 64 + iry,
                                 ilx * 64 + iry, irx * 64 + ily);
            wt4[oi]  = make_float4(glt, grb, glb, grt);
        }
    }
}

// ---------------- K2: AK conv as gather-fused bf16 MFMA GEMM ----------------
// D[co][pix] = sum_k W[co][k] * v[k][pix], K=768, block=(b,i): 64 pix, 256 co
__global__ __launch_bounds__(256) void ak_mfma_kernel(
    const float* __restrict__ x, const unsigned short* __restrict__ W,
    const int4* __restrict__ idx4, const float4* __restrict__ wt4,
    float* __restrict__ y)
{
    int blk = blockIdx.x;              // 512: b*64 + i
    int b = blk >> 6, i = blk & 63;
    int tid = threadIdx.x;
    int wv = tid >> 6, lane = tid & 63;
    int quad = lane >> 4, l15 = lane & 15;

    __shared__ __align__(16) unsigned short sA[8192];  // [kq][co][8]  16 KB
    __shared__ __align__(16) unsigned short sB[2048];  // [kq][pix][8]  4 KB

    int pixS = tid & 63, kqS = tid >> 6;
    int4 id[3]; float4 gw[3];
    #pragma unroll
    for (int n = 0; n < 3; ++n) {
        int oi = (b * 3 + n) * HW_ + i * 64 + pixS;
        id[n] = idx4[oi]; gw[n] = wt4[oi];
    }
    const float* xb = x + b * C_ * HW_;

    f32x4 acc[4][4];
    #pragma unroll
    for (int mt = 0; mt < 4; ++mt)
        #pragma unroll
        for (int nt = 0; nt < 4; ++nt) acc[mt][nt] = (f32x4){0.f, 0.f, 0.f, 0.f};

    for (int k0 = 0; k0 < 768; k0 += 32) {
        // stage A: 1024 segments of 8 bf16
        #pragma unroll
        for (int s = 0; s < 4; ++s) {
            int idxx = s * 256 + tid;
            int kq = idxx >> 8, co = idxx & 255;
            *(uint4*)&sA[(kq * 256 + co) * 8] =
                *(const uint4*)&W[co * 768 + k0 + kq * 8];
        }
        // stage B: compute 8 gathered-bilinear v values for (kqS, pixS)
        {
            int kk = k0 + kqS * 8;
            union { unsigned short h[8]; uint4 u; } hb;
            #pragma unroll
            for (int jj = 0; jj < 8; ++jj) {
                int k = kk + jj;
                int ci = k / 3;
                int n = k - ci * 3;
                const float* xp = xb + ci * HW_;
                float vv = gw[n].x * xp[id[n].x] + gw[n].y * xp[id[n].y]
                         + gw[n].z * xp[id[n].z] + gw[n].w * xp[id[n].w];
                hb.h[jj] = f2bf(vv);
            }
            *(uint4*)&sB[(kqS * 64 + pixS) * 8] = hb.u;
        }
        __syncthreads();
        short8 af[4], bf[4];
        #pragma unroll
        for (int mt = 0; mt < 4; ++mt)
            af[mt] = *(const short8*)&sA[(quad * 256 + wv * 64 + mt * 16 + l15) * 8];
        #pragma unroll
        for (int nt = 0; nt < 4; ++nt)
            bf[nt] = *(const short8*)&sB[(quad * 64 + nt * 16 + l15) * 8];
        #pragma unroll
        for (int mt = 0; mt < 4; ++mt)
            #pragma unroll
            for (int nt = 0; nt < 4; ++nt)
                acc[mt][nt] = __builtin_amdgcn_mfma_f32_16x16x32_bf16(
                    af[mt], bf[nt], acc[mt][nt], 0, 0, 0);
        __syncthreads();
    }
    #pragma unroll
    for (int mt = 0; mt < 4; ++mt) {
        #pragma unroll
        for (int r = 0; r < 4; ++r) {
            int co = wv * 64 + mt * 16 + quad * 4 + r;
            float* yp = y + (b * C_ + co) * HW_ + i * 64;
            #pragma unroll
            for (int nt = 0; nt < 4; ++nt)
                yp[nt * 16 + l15] = acc[mt][nt][r];
        }
    }
}

// ---------------- K3: BN stats (deterministic, no atomics) ------------------
__global__ __launch_bounds__(256) void bn_reduce_kernel(
    const float* __restrict__ y, const float* __restrict__ gamma,
    const float* __restrict__ beta, float* __restrict__ ss)
{
    int c = blockIdx.x, tid = threadIdx.x;
    float s1 = 0.f, s2 = 0.f;
    for (int b = 0; b < 8; ++b) {
        const float4* p = (const float4*)(y + (b * C_ + c) * HW_);
        for (int s = tid; s < 1024; s += 256) {
            float4 v = p[s];
            s1 += v.x + v.y + v.z + v.w;
            s2 += v.x * v.x + v.y * v.y + v.z * v.z + v.w * v.w;
        }
    }
    __shared__ float r1[256], r2[256];
    r1[tid] = s1; r2[tid] = s2; __syncthreads();
    for (int st = 128; st > 0; st >>= 1) {
        if (tid < st) { r1[tid] += r1[tid + st]; r2[tid] += r2[tid + st]; }
        __syncthreads();
    }
    if (tid == 0) {
        const float inv_n = 1.f / 32768.f;
        float m = r1[0] * inv_n;
        float var = r2[0] * inv_n - m * m;
        float sc = gamma[c] * rsqrtf(var + 1e-5f);
        ss[c] = sc; ss[256 + c] = beta[c] - m * sc;
    }
}

// ---------------- K4: BN apply + SiLU ---------------------------------------
__global__ __launch_bounds__(256) void bn_silu_kernel(
    const float4* __restrict__ yr, const float* __restrict__ ss,
    float4* __restrict__ y1)
{
    int gid = blockIdx.x * 256 + threadIdx.x;  // grid=8192
    int c = (gid >> 10) & 255;
    float a = ss[c], sh = ss[256 + c];
    float4 v = yr[gid];
    float4 o;
    o.x = silu_f(v.x * a + sh);
    o.y = silu_f(v.y * a + sh);
    o.z = silu_f(v.z * a + sh);
    o.w = silu_f(v.w * a + sh);
    y1[gid] = o;
}

// ---------------- K5: 5x5 depthwise, pad 2 ----------------------------------
__global__ __launch_bounds__(256) void dw5_kernel(
    const float* __restrict__ in, const float* __restrict__ w,
    const float* __restrict__ bias, float* __restrict__ out)
{
    int gid = blockIdx.x * 256 + threadIdx.x;   // grid = 32768
    int j = gid & 63, i = (gid >> 6) & 63;
    int bc = gid >> 12, c = bc & 255;
    const float* ip = in + bc * HW_;
    float acc = bias[c];
    #pragma unroll
    for (int di = 0; di < 5; ++di) {
        int ii = i + di - 2;
        if (ii < 0 || ii > 63) continue;
        #pragma unroll
        for (int dj = 0; dj < 5; ++dj) {
            int jj = j + dj - 2;
            if (jj < 0 || jj > 63) continue;
            acc += w[c * 25 + di * 5 + dj] * ip[ii * 64 + jj];
        }
    }
    out[gid] = acc;
}

// ---------------- K6: 7x7 depthwise, dilation 3, pad 9 ----------------------
__global__ __launch_bounds__(256) void dw7d3_kernel(
    const float* __restrict__ in, const float* __restrict__ w,
    const float* __restrict__ bias, float* __restrict__ out)
{
    int gid = blockIdx.x * 256 + threadIdx.x;   // grid = 32768
    int j = gid & 63, i = (gid >> 6) & 63;
    int bc = gid >> 12, c = bc & 255;
    const float* ip = in + bc * HW_;
    float acc = bias[c];
    #pragma unroll
    for (int ki = 0; ki < 7; ++ki) {
        int ii = i + 3 * ki - 9;
        if (ii < 0 || ii > 63) continue;
        #pragma unroll
        for (int kj = 0; kj < 7; ++kj) {
            int jj = j + 3 * kj - 9;
            if (jj < 0 || jj > 63) continue;
            acc += w[c * 49 + ki * 7 + kj] * ip[ii * 64 + jj];
        }
    }
    out[gid] = acc;
}

// ---------------- K7/K8: 1x1 conv bf16 MFMA GEMM ----------------------------
// MODE 0: out = (W@in + bias) * aux      MODE 1: out = W@in + bias + aux
template<int MODE>
__global__ __launch_bounds__(256) void gemm1x1_mfma(
    const float* __restrict__ in, const unsigned short* __restrict__ W,
    const float* __restrict__ bias, const float* __restrict__ aux,
    float* __restrict__ out)
{
    int blk = blockIdx.x;              // 512: b*64 + i
    int b = blk >> 6, i = blk & 63;
    int tid = threadIdx.x;
    int wv = tid >> 6, lane = tid & 63;
    int quad = lane >> 4, l15 = lane & 15;

    __shared__ __align__(16) unsigned short sA[8192];
    __shared__ __align__(16) unsigned short sB[2048];
    int pixS = tid & 63, kqS = tid >> 6;

    f32x4 acc[4][4];
    #pragma unroll
    for (int mt = 0; mt < 4; ++mt)
        #pragma unroll
        for (int nt = 0; nt < 4; ++nt) acc[mt][nt] = (f32x4){0.f, 0.f, 0.f, 0.f};

    for (int k0 = 0; k0 < 256; k0 += 32) {
        #pragma unroll
        for (int s = 0; s < 4; ++s) {
            int idxx = s * 256 + tid;
            int kq = idxx >> 8, co = idxx & 255;
            *(uint4*)&sA[(kq * 256 + co) * 8] =
                *(const uint4*)&W[co * 256 + k0 + kq * 8];
        }
        {
            union { unsigned short h[8]; uint4 u; } hb;
            const float* ip = in + (b * C_ + k0 + kqS * 8) * HW_ + i * 64 + pixS;
            #pragma unroll
            for (int jj = 0; jj < 8; ++jj) hb.h[jj] = f2bf(ip[jj * HW_]);
            *(uint4*)&sB[(kqS * 64 + pixS) * 8] = hb.u;
        }
        __syncthreads();
        short8 af[4], bf[4];
        #pragma unroll
        for (int mt = 0; mt < 4; ++mt)
            af[mt] = *(const short8*)&sA[(quad * 256 + wv * 64 + mt * 16 + l15) * 8];
        #pragma unroll
        for (int nt = 0; nt < 4; ++nt)
            bf[nt] = *(const short8*)&sB[(quad * 64 + nt * 16 + l15) * 8];
        #pragma unroll
        for (int mt = 0; mt < 4; ++mt)
            #pragma unroll
            for (int nt = 0; nt < 4; ++nt)
                acc[mt][nt] = __builtin_amdgcn_mfma_f32_16x16x32_bf16(
                    af[mt], bf[nt], acc[mt][nt], 0, 0, 0);
        __syncthreads();
    }
    #pragma unroll
    for (int mt = 0; mt < 4; ++mt) {
        #pragma unroll
        for (int r = 0; r < 4; ++r) {
            int co = wv * 64 + mt * 16 + quad * 4 + r;
            float bco = bias[co];
            long base = (long)(b * C_ + co) * HW_ + i * 64;
            #pragma unroll
            for (int nt = 0; nt < 4; ++nt) {
                int col = nt * 16 + l15;
                float o = acc[mt][nt][r] + bco;
                float a = aux[base + col];
                out[base + col] = (MODE == 0) ? o * a : o + a;
            }
        }
    }
}

// ---------------- launch ----------------------------------------------------
extern "C" void kernel_launch(void* const* d_in, const int* in_sizes, int n_in,
                              void* d_out, int out_size, void* d_ws, size_t ws_size,
                              hipStream_t stream) {
    const float* x     = (const float*)d_in[0];
    const float* p_w   = (const float*)d_in[1];
    const float* p_b   = (const float*)d_in[2];
    const float* ak_w  = (const float*)d_in[3];
    const float* ak_g  = (const float*)d_in[4];
    const float* ak_b  = (const float*)d_in[5];
    const float* l0_w  = (const float*)d_in[6];
    const float* l0_b  = (const float*)d_in[7];
    const float* ls_w  = (const float*)d_in[8];
    const float* ls_b  = (const float*)d_in[9];
    const float* l1_w  = (const float*)d_in[10];
    const float* l1_b  = (const float*)d_in[11];
    const float* cv_w  = (const float*)d_in[12];
    const float* cv_b  = (const float*)d_in[13];
    float* out = (float*)d_out;

    char* w = (char*)d_ws;
    int4*   idx4 = (int4*)w;                         // 1.5 MB
    float4* wt4  = (float4*)(w + 1572864);           // 1.5 MB
    float*  bufA = (float*)(w + 3145728);            // 32 MB
    float*  bufB = bufA + NELEM;                     // 32 MB
    float*  bufC = bufB + NELEM;                     // 32 MB
    unsigned short* wak = (unsigned short*)(w + 103809024);  // 384 KB
    unsigned short* wl1 = wak + 196608;              // 128 KB
    unsigned short* wcv = wl1 + 65536;               // 128 KB
    float* ss = (float*)(w + 104464384);             // 2 KB

    prep_kernel<<<1280, 256, 0, stream>>>(ak_w, l1_w, cv_w, wak, wl1, wcv);
    offset_idx_kernel<<<512, 256, 0, stream>>>(x, p_w, p_b, idx4, wt4);
    ak_mfma_kernel<<<512, 256, 0, stream>>>(x, wak, idx4, wt4, bufA);
    bn_reduce_kernel<<<256, 256, 0, stream>>>(bufA, ak_g, ak_b, ss);
    bn_silu_kernel<<<8192, 256, 0, stream>>>((const float4*)bufA, ss, (float4*)bufB);
    dw5_kernel<<<32768, 256, 0, stream>>>(bufB, l0_w, l0_b, bufA);
    dw7d3_kernel<<<32768, 256, 0, stream>>>(bufA, ls_w, ls_b, bufC);
    gemm1x1_mfma<0><<<512, 256, 0, stream>>>(bufC, wl1, l1_b, bufB, bufA);
    gemm1x1_mfma<1><<<512, 256, 0, stream>>>(bufA, wcv, cv_b, x, out);
}

// Round 3
// 385.308 us; speedup vs baseline: 3.8070x; 2.1238x over previous
//
#include <hip/hip_runtime.h>
#include <math.h>
#include <stdint.h>

#define B_ 8
#define C_ 256
#define HW_ 4096
#define NPIX 32768
#define NELEM (B_*C_*HW_)   // 8388608

typedef __attribute__((ext_vector_type(8))) short short8;
typedef __attribute__((ext_vector_type(4))) float f32x4;

__device__ __forceinline__ unsigned short f2bf(float f) {
    union { float f; uint32_t u; } v; v.f = f;
    uint32_t r = v.u + 0x7FFFu + ((v.u >> 16) & 1u);
    return (unsigned short)(r >> 16);
}
__device__ __forceinline__ float b2f(unsigned short h) {
    union { uint32_t u; float f; } v; v.u = ((uint32_t)h) << 16; return v.f;
}
__device__ __forceinline__ float silu_f(float v) { return v / (1.f + __expf(-v)); }

// ---------------- K0: fp32 -> bf16 weight conversion ------------------------
__global__ __launch_bounds__(256) void prep_kernel(
    const float* __restrict__ akw, const float* __restrict__ l1w,
    const float* __restrict__ cvw,
    unsigned short* __restrict__ wak, unsigned short* __restrict__ wl1,
    unsigned short* __restrict__ wcv)
{
    int gid = blockIdx.x * 256 + threadIdx.x;      // grid=1280
    if (gid < 196608) wak[gid] = f2bf(akw[gid]);
    else if (gid < 262144) { int g = gid - 196608; wl1[g] = f2bf(l1w[g]); }
    else { int g = gid - 262144; wcv[g] = f2bf(cvw[g]); }
}

// ---------------- K1a: offset conv stage 1 (per-32ch partials) --------------
__global__ __launch_bounds__(256) void offset_s1_kernel(
    const float* __restrict__ x, const float* __restrict__ pw,
    float* __restrict__ part)          // (4096 blocks, 6, 64)
{
    int blk = blockIdx.x;              // 4096 = (b*64+i)*8 + g
    int g = blk & 7, bi = blk >> 3;
    int b = bi >> 6, i = bi & 63;
    int tid = threadIdx.x;
    int sg = tid >> 6, j = tid & 63;

    float o[6] = {0.f, 0.f, 0.f, 0.f, 0.f, 0.f};
    const float* xb = x + ((size_t)b * C_ + g * 32 + sg * 8) * HW_;
    for (int t = 0; t < 8; ++t) {
        int ci = g * 32 + sg * 8 + t;
        const float* xp = xb + t * HW_;
        const float* wp = pw + ci * 9;
        #pragma unroll
        for (int ki = 0; ki < 3; ++ki) {
            int ii = i + ki - 1; if (ii < 0 || ii > 63) continue;
            #pragma unroll
            for (int kj = 0; kj < 3; ++kj) {
                int jj = j + kj - 1; if (jj < 0 || jj > 63) continue;
                float xv = xp[ii * 64 + jj];
                #pragma unroll
                for (int tt = 0; tt < 6; ++tt)
                    o[tt] += wp[tt * 2304 + ki * 3 + kj] * xv;
            }
        }
    }
    __shared__ float s_o[256 * 6];
    #pragma unroll
    for (int tt = 0; tt < 6; ++tt) s_o[tid * 6 + tt] = o[tt];
    __syncthreads();
    for (int idx = tid; idx < 384; idx += 256) {
        int tt = idx >> 6, jj = idx & 63;
        float s = s_o[jj * 6 + tt] + s_o[(64 + jj) * 6 + tt]
                + s_o[(128 + jj) * 6 + tt] + s_o[(192 + jj) * 6 + tt];
        part[(size_t)blk * 384 + idx] = s;
    }
}

// ---------------- K1b: offset stage 2 -> bilinear tables --------------------
__global__ __launch_bounds__(256) void offset_s2_kernel(
    const float* __restrict__ part, const float* __restrict__ pb,
    int4* __restrict__ idx4, float4* __restrict__ wt4)
{
    int pix = blockIdx.x * 256 + threadIdx.x;   // grid=128
    int b = pix >> 12, rem = pix & 4095, i = rem >> 6, j = rem & 63;
    int bi = b * 64 + i;
    float v[6];
    #pragma unroll
    for (int tt = 0; tt < 6; ++tt) v[tt] = pb[tt];
    for (int g = 0; g < 8; ++g) {
        const float* pp = part + ((size_t)bi * 8 + g) * 384;
        #pragma unroll
        for (int tt = 0; tt < 6; ++tt) v[tt] += pp[tt * 64 + j];
    }
    const float pnx[3] = {0.f, 0.f, 1.f};
    const float pny[3] = {0.f, 1.f, 0.f};
    #pragma unroll
    for (int n = 0; n < 3; ++n) {
        float px_ = (float)i + pnx[n] + v[n];
        float py_ = (float)j + pny[n] + v[n + 3];
        float qx = floorf(px_), qy = floorf(py_);
        float qlx = fminf(fmaxf(qx,       0.f), 63.f);
        float qly = fminf(fmaxf(qy,       0.f), 63.f);
        float qrx = fminf(fmaxf(qx + 1.f, 0.f), 63.f);
        float qry = fminf(fmaxf(qy + 1.f, 0.f), 63.f);
        float pxc = fminf(fmaxf(px_,      0.f), 63.f);
        float pyc = fminf(fmaxf(py_,      0.f), 63.f);
        float glt = (1.f + (qlx - pxc)) * (1.f + (qly - pyc));
        float grb = (1.f - (qrx - pxc)) * (1.f - (qry - pyc));
        float glb = (1.f + (qlx - pxc)) * (1.f - (qry - pyc));
        float grt = (1.f - (qrx - pxc)) * (1.f + (qly - pyc));
        int ilx = (int)qlx, ily = (int)qly, irx = (int)qrx, iry = (int)qry;
        int oi = (b * 3 + n) * HW_ + i * 64 + j;
        idx4[oi] = make_int4(ilx * 64 + ily, irx * 64 + iry,
                             ilx * 64 + iry, irx * 64 + ily);
        wt4[oi]  = make_float4(glt, grb, glb, grt);
    }
}

// ---------------- K2a: bilinear gather -> v bf16 [768][32768] ---------------
__global__ __launch_bounds__(256) void gather_kernel(
    const float* __restrict__ x, const int4* __restrict__ idx4,
    const float4* __restrict__ wt4, unsigned short* __restrict__ v)
{
    int blk = blockIdx.x;          // 2048 = bi*4 + cg
    int cg = blk & 3, bi = blk >> 2;
    int b = bi >> 6, i = bi & 63;
    int tid = threadIdx.x;
    int j = tid & 63, sg = tid >> 6;

    int4 id[3]; float4 gw[3];
    #pragma unroll
    for (int n = 0; n < 3; ++n) {
        int oi = (b * 3 + n) * HW_ + i * 64 + j;
        id[n] = idx4[oi]; gw[n] = wt4[oi];
    }
    const float* xb = x + (size_t)b * C_ * HW_;
    int pix = bi * 64 + j;
    for (int t = 0; t < 16; ++t) {
        int ci = cg * 64 + sg * 16 + t;
        const float* xp = xb + ci * HW_;
        #pragma unroll
        for (int n = 0; n < 3; ++n) {
            float vv = gw[n].x * xp[id[n].x] + gw[n].y * xp[id[n].y]
                     + gw[n].z * xp[id[n].z] + gw[n].w * xp[id[n].w];
            v[(size_t)(ci * 3 + n) * NPIX + pix] = f2bf(vv);
        }
    }
}

// ---------------- K2b: AK GEMM (bf16 MFMA), K=768 ---------------------------
__global__ __launch_bounds__(256) void ak_mfma_kernel(
    const unsigned short* __restrict__ v, const unsigned short* __restrict__ W,
    float* __restrict__ y)
{
    int blk = blockIdx.x;              // 512 = b*64 + i
    int b = blk >> 6, i = blk & 63;
    int tid = threadIdx.x;
    int wv = tid >> 6, lane = tid & 63;
    int quad = lane >> 4, l15 = lane & 15;
    __shared__ __align__(16) unsigned short sA[8192];  // [kq][co][8]
    __shared__ __align__(16) unsigned short sB[2048];  // [kq][pix][8]
    int pixS = tid & 63, kqS = tid >> 6;
    int pix0 = blk * 64;

    f32x4 acc[4][4];
    #pragma unroll
    for (int mt = 0; mt < 4; ++mt)
        #pragma unroll
        for (int nt = 0; nt < 4; ++nt) acc[mt][nt] = (f32x4){0.f, 0.f, 0.f, 0.f};

    for (int k0 = 0; k0 < 768; k0 += 32) {
        #pragma unroll
        for (int s = 0; s < 4; ++s) {
            int idxx = s * 256 + tid;
            int kq = idxx >> 8, co = idxx & 255;
            *(uint4*)&sA[(kq * 256 + co) * 8] =
                *(const uint4*)&W[co * 768 + k0 + kq * 8];
        }
        {
            const unsigned short* vp = v + (size_t)(k0 + kqS * 8) * NPIX + pix0 + pixS;
            union { unsigned short h[8]; uint4 u; } hb;
            #pragma unroll
            for (int jj = 0; jj < 8; ++jj) hb.h[jj] = vp[(size_t)jj * NPIX];
            *(uint4*)&sB[(kqS * 64 + pixS) * 8] = hb.u;
        }
        __syncthreads();
        short8 af[4], bf[4];
        #pragma unroll
        for (int mt = 0; mt < 4; ++mt)
            af[mt] = *(const short8*)&sA[(quad * 256 + wv * 64 + mt * 16 + l15) * 8];
        #pragma unroll
        for (int nt = 0; nt < 4; ++nt)
            bf[nt] = *(const short8*)&sB[(quad * 64 + nt * 16 + l15) * 8];
        #pragma unroll
        for (int mt = 0; mt < 4; ++mt)
            #pragma unroll
            for (int nt = 0; nt < 4; ++nt)
                acc[mt][nt] = __builtin_amdgcn_mfma_f32_16x16x32_bf16(
                    af[mt], bf[nt], acc[mt][nt], 0, 0, 0);
        __syncthreads();
    }
    #pragma unroll
    for (int mt = 0; mt < 4; ++mt) {
        #pragma unroll
        for (int r = 0; r < 4; ++r) {
            int co = wv * 64 + mt * 16 + quad * 4 + r;
            float* yp = y + ((size_t)b * C_ + co) * HW_ + i * 64;
            #pragma unroll
            for (int nt = 0; nt < 4; ++nt)
                yp[nt * 16 + l15] = acc[mt][nt][r];
        }
    }
}

// ---------------- K3a: BN partials (deterministic) --------------------------
__global__ __launch_bounds__(256) void bn_part_kernel(
    const float* __restrict__ y, float* __restrict__ p1, float* __restrict__ p2)
{
    int blk = blockIdx.x;          // 2048 = c*8 + b
    int c = blk >> 3, b = blk & 7;
    int tid = threadIdx.x;
    const float4* p = (const float4*)(y + ((size_t)b * C_ + c) * HW_);
    float s1 = 0.f, s2 = 0.f;
    for (int s = tid; s < 1024; s += 256) {
        float4 v = p[s];
        s1 += v.x + v.y + v.z + v.w;
        s2 += v.x * v.x + v.y * v.y + v.z * v.z + v.w * v.w;
    }
    __shared__ float r1[256], r2[256];
    r1[tid] = s1; r2[tid] = s2; __syncthreads();
    for (int st = 128; st > 0; st >>= 1) {
        if (tid < st) { r1[tid] += r1[tid + st]; r2[tid] += r2[tid + st]; }
        __syncthreads();
    }
    if (tid == 0) { p1[blk] = r1[0]; p2[blk] = r2[0]; }
}

// ---------------- K3b: BN stats -> scale/shift ------------------------------
__global__ __launch_bounds__(256) void bn_stats_kernel(
    const float* __restrict__ p1, const float* __restrict__ p2,
    const float* __restrict__ gamma, const float* __restrict__ beta,
    float* __restrict__ ss)
{
    int c = threadIdx.x;
    float s1 = 0.f, s2 = 0.f;
    #pragma unroll
    for (int b = 0; b < 8; ++b) { s1 += p1[c * 8 + b]; s2 += p2[c * 8 + b]; }
    const float inv_n = 1.f / (float)NPIX;
    float m = s1 * inv_n;
    float var = s2 * inv_n - m * m;
    float sc = gamma[c] * rsqrtf(var + 1e-5f);
    ss[c] = sc; ss[256 + c] = beta[c] - m * sc;
}

// ---------------- K4: fused BN+SiLU + 5x5 depthwise (LDS tile) --------------
__global__ __launch_bounds__(256) void dw5_fused_kernel(
    const float* __restrict__ in, const float* __restrict__ ss,
    const float* __restrict__ w, const float* __restrict__ bias,
    unsigned short* __restrict__ out)
{
    int bc = blockIdx.x;           // 2048 = b*256 + c
    int c = bc & 255;
    int tid = threadIdx.x;
    __shared__ float tile[68 * 68];
    float sc = ss[c], sh = ss[256 + c];
    const float* ip = in + (size_t)bc * HW_;
    for (int s = tid; s < 68 * 68; s += 256) {
        int r = s / 68, cc = s - r * 68;
        int ii = r - 2, jj = cc - 2;
        float vv = 0.f;
        if (ii >= 0 && ii < 64 && jj >= 0 && jj < 64) {
            float t = ip[ii * 64 + jj] * sc + sh;
            vv = silu_f(t);
        }
        tile[s] = vv;
    }
    float wr[25];
    #pragma unroll
    for (int t = 0; t < 25; ++t) wr[t] = w[c * 25 + t];
    float bv = bias[c];
    __syncthreads();
    int j0 = (tid & 15) * 4, ig = tid >> 4;
    unsigned short* op = out + (size_t)bc * HW_;
    for (int r = 0; r < 4; ++r) {
        int i = r * 16 + ig;
        float o0 = bv, o1 = bv, o2 = bv, o3 = bv;
        #pragma unroll
        for (int di = 0; di < 5; ++di) {
            const float* tp = &tile[(i + di) * 68 + j0];
            float4 a = *(const float4*)tp;
            float4 bq = *(const float4*)(tp + 4);
            float vv[8] = {a.x, a.y, a.z, a.w, bq.x, bq.y, bq.z, bq.w};
            #pragma unroll
            for (int dj = 0; dj < 5; ++dj) {
                float wv = wr[di * 5 + dj];
                o0 += wv * vv[dj];     o1 += wv * vv[dj + 1];
                o2 += wv * vv[dj + 2]; o3 += wv * vv[dj + 3];
            }
        }
        union { unsigned short h[4]; uint2 u; } pk;
        pk.h[0] = f2bf(o0); pk.h[1] = f2bf(o1);
        pk.h[2] = f2bf(o2); pk.h[3] = f2bf(o3);
        *(uint2*)&op[i * 64 + j0] = pk.u;
    }
}

// ---------------- K5: 7x7 dilated(3) depthwise (LDS tile) -------------------
__global__ __launch_bounds__(256) void dw7d3_kernel(
    const unsigned short* __restrict__ in, const float* __restrict__ w,
    const float* __restrict__ bias, unsigned short* __restrict__ out)
{
    int bc = blockIdx.x;           // 2048
    int c = bc & 255;
    int tid = threadIdx.x;
    __shared__ float tile[82 * 84];
    const unsigned short* ip = in + (size_t)bc * HW_;
    for (int s = tid; s < 82 * 84; s += 256) {
        int r = s / 84, cc = s - r * 84;
        int ii = r - 9, jj = cc - 9;
        float vv = 0.f;
        if (ii >= 0 && ii < 64 && jj >= 0 && jj < 64) vv = b2f(ip[ii * 64 + jj]);
        tile[s] = vv;
    }
    float wr[49];
    #pragma unroll
    for (int t = 0; t < 49; ++t) wr[t] = w[c * 49 + t];
    float bv = bias[c];
    __syncthreads();
    int j0 = (tid & 15) * 4, ig = tid >> 4;
    unsigned short* op = out + (size_t)bc * HW_;
    for (int r = 0; r < 4; ++r) {
        int i = r * 16 + ig;
        float o0 = bv, o1 = bv, o2 = bv, o3 = bv;
        #pragma unroll
        for (int di = 0; di < 7; ++di) {
            const float* tp = &tile[(i + 3 * di) * 84 + j0];
            float vv[24];
            #pragma unroll
            for (int q = 0; q < 6; ++q)
                *(float4*)&vv[q * 4] = *(const float4*)(tp + q * 4);
            #pragma unroll
            for (int dj = 0; dj < 7; ++dj) {
                float wv = wr[di * 7 + dj];
                o0 += wv * vv[3 * dj];     o1 += wv * vv[3 * dj + 1];
                o2 += wv * vv[3 * dj + 2]; o3 += wv * vv[3 * dj + 3];
            }
        }
        union { unsigned short h[4]; uint2 u; } pk;
        pk.h[0] = f2bf(o0); pk.h[1] = f2bf(o1);
        pk.h[2] = f2bf(o2); pk.h[3] = f2bf(o3);
        *(uint2*)&op[i * 64 + j0] = pk.u;
    }
}

// ---------------- K6/K7: 1x1 conv bf16 MFMA GEMM ----------------------------
// MODE 0: out_bf = (W@in + bias) * silu(aux*sc+sh)   (lka 1x1 * u)
// MODE 1: out_f  = W@in + bias + aux                 (final conv + residual)
template<int MODE>
__global__ __launch_bounds__(256) void gemm1x1_mfma(
    const unsigned short* __restrict__ in, const unsigned short* __restrict__ W,
    const float* __restrict__ bias, const float* __restrict__ aux,
    const float* __restrict__ ss,
    unsigned short* __restrict__ out_bf, float* __restrict__ out_f)
{
    int blk = blockIdx.x;              // 512 = b*64 + i
    int b = blk >> 6, i = blk & 63;
    int tid = threadIdx.x;
    int wv = tid >> 6, lane = tid & 63;
    int quad = lane >> 4, l15 = lane & 15;
    __shared__ __align__(16) unsigned short sA[8192];
    __shared__ __align__(16) unsigned short sB[2048];
    int pixS = tid & 63, kqS = tid >> 6;

    f32x4 acc[4][4];
    #pragma unroll
    for (int mt = 0; mt < 4; ++mt)
        #pragma unroll
        for (int nt = 0; nt < 4; ++nt) acc[mt][nt] = (f32x4){0.f, 0.f, 0.f, 0.f};

    for (int k0 = 0; k0 < 256; k0 += 32) {
        #pragma unroll
        for (int s = 0; s < 4; ++s) {
            int idxx = s * 256 + tid;
            int kq = idxx >> 8, co = idxx & 255;
            *(uint4*)&sA[(kq * 256 + co) * 8] =
                *(const uint4*)&W[co * 256 + k0 + kq * 8];
        }
        {
            const unsigned short* vp =
                in + ((size_t)b * C_ + k0 + kqS * 8) * HW_ + i * 64 + pixS;
            union { unsigned short h[8]; uint4 u; } hb;
            #pragma unroll
            for (int jj = 0; jj < 8; ++jj) hb.h[jj] = vp[(size_t)jj * HW_];
            *(uint4*)&sB[(kqS * 64 + pixS) * 8] = hb.u;
        }
        __syncthreads();
        short8 af[4], bf[4];
        #pragma unroll
        for (int mt = 0; mt < 4; ++mt)
            af[mt] = *(const short8*)&sA[(quad * 256 + wv * 64 + mt * 16 + l15) * 8];
        #pragma unroll
        for (int nt = 0; nt < 4; ++nt)
            bf[nt] = *(const short8*)&sB[(quad * 64 + nt * 16 + l15) * 8];
        #pragma unroll
        for (int mt = 0; mt < 4; ++mt)
            #pragma unroll
            for (int nt = 0; nt < 4; ++nt)
                acc[mt][nt] = __builtin_amdgcn_mfma_f32_16x16x32_bf16(
                    af[mt], bf[nt], acc[mt][nt], 0, 0, 0);
        __syncthreads();
    }
    #pragma unroll
    for (int mt = 0; mt < 4; ++mt) {
        #pragma unroll
        for (int r = 0; r < 4; ++r) {
            int co = wv * 64 + mt * 16 + quad * 4 + r;
            float bco = bias[co];
            size_t base = ((size_t)b * C_ + co) * HW_ + i * 64;
            if (MODE == 0) {
                float sc = ss[co], sh = ss[256 + co];
                #pragma unroll
                for (int nt = 0; nt < 4; ++nt) {
                    int col = nt * 16 + l15;
                    float o = acc[mt][nt][r] + bco;
                    float u = silu_f(aux[base + col] * sc + sh);
                    out_bf[base + col] = f2bf(o * u);
                }
            } else {
                #pragma unroll
                for (int nt = 0; nt < 4; ++nt) {
                    int col = nt * 16 + l15;
                    out_f[base + col] = acc[mt][nt][r] + bco + aux[base + col];
                }
            }
        }
    }
}

// ---------------- launch ----------------------------------------------------
extern "C" void kernel_launch(void* const* d_in, const int* in_sizes, int n_in,
                              void* d_out, int out_size, void* d_ws, size_t ws_size,
                              hipStream_t stream) {
    const float* x     = (const float*)d_in[0];
    const float* p_w   = (const float*)d_in[1];
    const float* p_b   = (const float*)d_in[2];
    const float* ak_w  = (const float*)d_in[3];
    const float* ak_g  = (const float*)d_in[4];
    const float* ak_b  = (const float*)d_in[5];
    const float* l0_w  = (const float*)d_in[6];
    const float* l0_b  = (const float*)d_in[7];
    const float* ls_w  = (const float*)d_in[8];
    const float* ls_b  = (const float*)d_in[9];
    const float* l1_w  = (const float*)d_in[10];
    const float* l1_b  = (const float*)d_in[11];
    const float* cv_w  = (const float*)d_in[12];
    const float* cv_b  = (const float*)d_in[13];
    float* out = (float*)d_out;

    char* w = (char*)d_ws;
    // [0 .. 3145728): idx4 + wt4 tables (dead after gather; bn partials + ss reuse head)
    int4*   idx4 = (int4*)w;                          // 1.5 MB
    float4* wt4  = (float4*)(w + 1572864);            // 1.5 MB
    float*  p1   = (float*)w;                         // 8 KB  (after gather)
    float*  p2   = (float*)(w + 8192);                // 8 KB
    float*  ss   = (float*)(w + 16384);               // 2 KB
    unsigned short* wak = (unsigned short*)(w + 3145728);   // 384 KB
    unsigned short* wl1 = (unsigned short*)(w + 3538944);   // 128 KB
    unsigned short* wcv = (unsigned short*)(w + 3670016);   // 128 KB
    // R1 region at 3801088: part (6.3 MB) -> v (48 MB) -> dw5out/g0out bf16
    char* R1 = w + 3801088;
    float* part = (float*)R1;                          // 6.3 MB (dead before gather)
    unsigned short* v = (unsigned short*)R1;           // 48 MB (dead after ak_mfma)
    unsigned short* dw5out = (unsigned short*)R1;            // 16 MB
    unsigned short* g0out  = (unsigned short*)(R1 + 16777216); // 16 MB
    float* bufA = (float*)(w + 54132736);              // 32 MB (y_raw fp32)
    unsigned short* attn = (unsigned short*)(w + 87687168);  // 16 MB
    // total = 104,464,384 bytes

    prep_kernel<<<1280, 256, 0, stream>>>(ak_w, l1_w, cv_w, wak, wl1, wcv);
    offset_s1_kernel<<<4096, 256, 0, stream>>>(x, p_w, part);
    offset_s2_kernel<<<128, 256, 0, stream>>>(part, p_b, idx4, wt4);
    gather_kernel<<<2048, 256, 0, stream>>>(x, idx4, wt4, v);
    ak_mfma_kernel<<<512, 256, 0, stream>>>(v, wak, bufA);
    bn_part_kernel<<<2048, 256, 0, stream>>>(bufA, p1, p2);
    bn_stats_kernel<<<1, 256, 0, stream>>>(p1, p2, ak_g, ak_b, ss);
    dw5_fused_kernel<<<2048, 256, 0, stream>>>(bufA, ss, l0_w, l0_b, dw5out);
    dw7d3_kernel<<<2048, 256, 0, stream>>>(dw5out, ls_w, ls_b, attn);
    gemm1x1_mfma<0><<<512, 256, 0, stream>>>(attn, wl1, l1_b, bufA, ss, g0out, nullptr);
    gemm1x1_mfma<1><<<512, 256, 0, stream>>>(g0out, wcv, cv_b, x, nullptr, nullptr, out);
}